// Round 1
// baseline (581.070 us; speedup 1.0000x reference)
//
#include <hip/hip_runtime.h>
#include <hip/hip_bf16.h>

typedef unsigned int uint;
typedef unsigned short ushort;
typedef __attribute__((ext_vector_type(8))) short bf16x8;
typedef __attribute__((ext_vector_type(4))) float f32x4;

#define LX 264   // padded lds_x row (bf16 elems): 2-way banks on b128 reads
#define LW 40    // padded lds_w row (bf16 elems)

__device__ __forceinline__ float bf2f(ushort u) {
    return __uint_as_float(((uint)u) << 16);
}
__device__ __forceinline__ ushort f2bf(float f) {
    uint u = __float_as_uint(f);
    u += 0x7FFFu + ((u >> 16) & 1u);   // round-to-nearest-even
    return (ushort)(u >> 16);
}
__device__ __forceinline__ float sigm(float x) {
    return 1.0f / (1.0f + expf(-x));
}

// ---------------- kernel 1: P[v][g] = tanh(emb[v]) @ w_ih^T + b_ih  [96,512]
__global__ void kP(const float* __restrict__ emb, const float* __restrict__ w_ih,
                   const float* __restrict__ b_ih, float* __restrict__ P)
{
    __shared__ __align__(16) float te[300];
    int v = blockIdx.x, tid = threadIdx.x;          // block 512
    for (int k = tid; k < 300; k += 512) te[k] = tanhf(emb[v * 300 + k]);
    __syncthreads();
    int g = tid;
    float acc = b_ih[g];
    const float4* wr = (const float4*)(w_ih + g * 300);   // 300*4B row: 16B-aligned
    const float4* tv = (const float4*)te;
    for (int k = 0; k < 75; ++k) {
        float4 w4 = wr[k], t4 = tv[k];
        acc += w4.x * t4.x + w4.y * t4.y + w4.z * t4.z + w4.w * t4.w;
    }
    P[v * 512 + g] = acc;
}

// ---------------- kernel 2: Wstage[li][kc][n][kk] = bf16(gw[kc*32+kk][n])
__global__ void kW(const float* __restrict__ g_w2, const float* __restrict__ g_w3,
                   const float* __restrict__ g_w4, ushort* __restrict__ Wst)
{
    int li = blockIdx.x >> 3, kc = blockIdx.x & 7, n = threadIdx.x;  // block 256
    const float* W = (li == 0) ? g_w2 : (li == 1) ? g_w3 : g_w4;
    ushort* dst = Wst + li * 65536 + kc * 8192 + n * 32;
    for (int kk = 0; kk < 32; ++kk)
        dst[kk] = f2bf(W[(kc * 32 + kk) * 256 + n]);
}

// ---------------- kernel 3: LSTM (final cell state) -> Wq[b] = c@W1c + g_b1
__global__ void kLSTM(const float* __restrict__ P, const float* __restrict__ w_hh,
                      const float* __restrict__ b_hh, const float* __restrict__ g_w1,
                      const float* __restrict__ g_b1, const int* __restrict__ q_feats,
                      const int* __restrict__ q_lens, float* __restrict__ Wq)
{
    __shared__ __align__(16) float h[128];
    __shared__ __align__(16) float c[128];
    __shared__ float gates[512];
    int b = blockIdx.x, tid = threadIdx.x;          // block 256
    if (tid < 128) { h[tid] = 0.f; c[tid] = 0.f; }
    __syncthreads();
    int len = q_lens[b];
    for (int t = 0; t < 20; ++t) {
        int idx = q_feats[b * 20 + t];
        for (int g = tid; g < 512; g += 256) {
            float acc = P[idx * 512 + g] + b_hh[g];
            const float4* wr = (const float4*)(w_hh + g * 128);
            const float4* hv = (const float4*)h;
            #pragma unroll 8
            for (int k = 0; k < 32; ++k) {
                float4 w4 = wr[k], h4 = hv[k];
                acc += w4.x * h4.x + w4.y * h4.y + w4.z * h4.z + w4.w * h4.w;
            }
            gates[g] = acc;
        }
        __syncthreads();
        if (tid < 128 && t < len) {
            float ig = sigm(gates[tid]);
            float fg = sigm(gates[128 + tid]);
            float gg = tanhf(gates[256 + tid]);
            float og = sigm(gates[384 + tid]);
            float cn = fg * c[tid] + ig * gg;
            c[tid] = cn;
            h[tid] = og * tanhf(cn);
        }
        __syncthreads();
    }
    // Wq[b][l] = g_b1[l] + sum_h c[h] * g_w1[(52+h)][l]
    int l = tid;
    float acc = g_b1[l];
    for (int k = 0; k < 128; ++k) acc += c[k] * g_w1[(52 + k) * 256 + l];
    Wq[b * 256 + l] = acc;
}

// ---------------- kernel 4: A1/A2 layer-1 partials per (b,n)
__global__ void kA(const float* __restrict__ box_feats, const float* __restrict__ g_w1,
                   const float* __restrict__ Wq, ushort* __restrict__ A1,
                   ushort* __restrict__ A2)
{
    __shared__ float box[26];
    int bn = blockIdx.x;                 // b*64+n
    int b = bn >> 6, n = bn & 63;
    int tid = threadIdx.x;               // block 256
    if (tid < 24)       box[tid] = box_feats[bn * 24 + tid];
    else if (tid == 24) box[24] = ((n >> 3) - 4) * 0.125f;   // (i - W/2)/W
    else if (tid == 25) box[25] = ((n & 7) - 4) * 0.125f;
    __syncthreads();
    int l = tid;
    float a1 = 0.f, a2 = Wq[b * 256 + l];
    #pragma unroll
    for (int d = 0; d < 26; ++d) {
        float bx = box[d];
        a1 += bx * g_w1[d * 256 + l];
        a2 += bx * g_w1[(26 + d) * 256 + l];
    }
    A1[bn * 256 + l] = f2bf(a1);
    A2[bn * 256 + l] = f2bf(a2);
}

// ---------------- kernel 5: main fused pair-MLP (layers 2-4, MFMA) + row reduce
__global__ __launch_bounds__(256, 3) void kD(
    const ushort* __restrict__ A1, const ushort* __restrict__ A2,
    const ushort* __restrict__ Wst,
    const float* __restrict__ b2, const float* __restrict__ b3,
    const float* __restrict__ b4, float* __restrict__ partial)
{
    __shared__ __align__(16) ushort lds_x[64 * LX];   // 33792 B
    __shared__ __align__(16) ushort lds_w[256 * LW];  // 20480 B

    const int tid = threadIdx.x;
    const int b = blockIdx.x >> 6, i = blockIdx.x & 63;
    const int lane = tid & 63, wv = tid >> 6;
    const int l15 = lane & 15, lg = lane >> 4;
    const int row0 = (wv & 1) * 32, col0 = (wv >> 1) * 128;

    // stage A1 row (f32) into alias of lds_w (free until first W staging)
    float* a1s = (float*)lds_w;
    a1s[tid] = bf2f(A1[(b * 64 + i) * 256 + tid]);
    __syncthreads();

    // X1[j][l] = relu(a1[l] + A2[b,j][l]) -> bf16 into lds_x
    const ushort* A2b = A2 + b * 64 * 256;
    #pragma unroll
    for (int p = 0; p < 8; ++p) {
        int task = p * 256 + tid;
        int j = task >> 5, l0 = (task & 31) << 3;
        uint4 v = *(const uint4*)(A2b + j * 256 + l0);
        uint vv[4] = {v.x, v.y, v.z, v.w};
        uint ov[4];
        #pragma unroll
        for (int q = 0; q < 4; ++q) {
            float f0 = a1s[l0 + 2 * q]     + bf2f((ushort)(vv[q] & 0xFFFFu));
            float f1 = a1s[l0 + 2 * q + 1] + bf2f((ushort)(vv[q] >> 16));
            f0 = fmaxf(f0, 0.f); f1 = fmaxf(f1, 0.f);
            ov[q] = (uint)f2bf(f0) | ((uint)f2bf(f1) << 16);
        }
        *(uint4*)&lds_x[j * LX + l0] = make_uint4(ov[0], ov[1], ov[2], ov[3]);
    }
    __syncthreads();

    #pragma unroll 1
    for (int li = 0; li < 3; ++li) {
        const ushort* Wl = Wst + li * 65536;
        const float* bias = (li == 0) ? b2 : (li == 1) ? b3 : b4;
        f32x4 acc[2][8];
        #pragma unroll
        for (int ct = 0; ct < 8; ++ct) {
            float bv = bias[col0 + ct * 16 + l15];
            f32x4 bx = {bv, bv, bv, bv};
            acc[0][ct] = bx; acc[1][ct] = bx;
        }
        for (int kc = 0; kc < 8; ++kc) {
            __syncthreads();                       // prev chunk fully consumed
            const uint4* src = (const uint4*)(Wl + kc * 8192 + tid * 32);
            uint4 w0 = src[0], w1 = src[1], w2 = src[2], w3 = src[3];
            uint4* dst = (uint4*)&lds_w[tid * LW];  // byte 80*t, 16B aligned
            dst[0] = w0; dst[1] = w1; dst[2] = w2; dst[3] = w3;
            __syncthreads();
            bf16x8 af0 = *(const bf16x8*)&lds_x[(row0 + l15) * LX + kc * 32 + lg * 8];
            bf16x8 af1 = *(const bf16x8*)&lds_x[(row0 + 16 + l15) * LX + kc * 32 + lg * 8];
            #pragma unroll
            for (int ct = 0; ct < 8; ++ct) {
                bf16x8 bfv = *(const bf16x8*)&lds_w[(col0 + ct * 16 + l15) * LW + lg * 8];
                acc[0][ct] = __builtin_amdgcn_mfma_f32_16x16x32_bf16(af0, bfv, acc[0][ct], 0, 0, 0);
                acc[1][ct] = __builtin_amdgcn_mfma_f32_16x16x32_bf16(af1, bfv, acc[1][ct], 0, 0, 0);
            }
        }
        // relu
        #pragma unroll
        for (int rt = 0; rt < 2; ++rt)
            #pragma unroll
            for (int ct = 0; ct < 8; ++ct)
                #pragma unroll
                for (int r = 0; r < 4; ++r)
                    acc[rt][ct][r] = fmaxf(acc[rt][ct][r], 0.f);

        if (li < 2) {
            __syncthreads();   // all waves done reading lds_x this layer
            #pragma unroll
            for (int rt = 0; rt < 2; ++rt)
                #pragma unroll
                for (int ct = 0; ct < 8; ++ct)
                    #pragma unroll
                    for (int r = 0; r < 4; ++r)
                        lds_x[(row0 + rt * 16 + lg * 4 + r) * LX + col0 + ct * 16 + l15]
                            = f2bf(acc[rt][ct][r]);
            __syncthreads();
        } else {
            // reduce over the block's 64 rows, deterministically
            __syncthreads();   // done reading lds_x; reuse as f32 scratch
            float* red = (float*)lds_x;
            float s[8];
            #pragma unroll
            for (int ct = 0; ct < 8; ++ct) {
                s[ct] = acc[0][ct][0] + acc[0][ct][1] + acc[0][ct][2] + acc[0][ct][3]
                      + acc[1][ct][0] + acc[1][ct][1] + acc[1][ct][2] + acc[1][ct][3];
                s[ct] += __shfl_xor(s[ct], 16, 64);
                s[ct] += __shfl_xor(s[ct], 32, 64);
            }
            if (lane < 16) {
                #pragma unroll
                for (int ct = 0; ct < 8; ++ct)
                    red[wv * 128 + ct * 16 + l15] = s[ct];
            }
            __syncthreads();
            int col = tid;
            int pair = col >> 7;
            float v0 = red[(pair * 2 + 0) * 128 + (col & 127)];
            float v1 = red[(pair * 2 + 1) * 128 + (col & 127)];
            partial[blockIdx.x * 256 + col] = v0 + v1;
        }
    }
}

// ---------------- kernel 6: g_out[b][col] = sum_i partial[(b,i)][col]
__global__ void kR(const float* __restrict__ partial, float* __restrict__ gout)
{
    int b = blockIdx.x, col = threadIdx.x;     // block 256
    float s = 0.f;
    for (int i = 0; i < 64; ++i) s += partial[(b * 64 + i) * 256 + col];
    gout[b * 256 + col] = s;
}

// ---------------- kernel 7: f-network
__global__ void kF(const float* __restrict__ gout,
                   const float* __restrict__ f_w1, const float* __restrict__ f_b1,
                   const float* __restrict__ f_w2, const float* __restrict__ f_b2,
                   const float* __restrict__ f_w3, const float* __restrict__ f_b3,
                   float* __restrict__ out)
{
    __shared__ float g[256], y1[256], y2[256];
    int b = blockIdx.x, t = threadIdx.x;       // block 256
    g[t] = gout[b * 256 + t];
    __syncthreads();
    float acc = f_b1[t];
    for (int k = 0; k < 256; ++k) acc += g[k] * f_w1[k * 256 + t];
    y1[t] = fmaxf(acc, 0.f);
    __syncthreads();
    acc = f_b2[t];
    for (int k = 0; k < 256; ++k) acc += y1[k] * f_w2[k * 256 + t];
    y2[t] = fmaxf(acc, 0.f);
    __syncthreads();
    if (t < 100) {
        float o = f_b3[t];
        for (int k = 0; k < 256; ++k) o += y2[k] * f_w3[k * 100 + t];
        out[b * 100 + t] = o;
    }
}

extern "C" void kernel_launch(void* const* d_in, const int* in_sizes, int n_in,
                              void* d_out, int out_size, void* d_ws, size_t ws_size,
                              hipStream_t stream)
{
    const float* box_feats = (const float*)d_in[0];
    const float* emb   = (const float*)d_in[1];
    const float* w_ih  = (const float*)d_in[2];
    const float* w_hh  = (const float*)d_in[3];
    const float* b_ih  = (const float*)d_in[4];
    const float* b_hh  = (const float*)d_in[5];
    const float* g_w1  = (const float*)d_in[6];
    const float* g_b1  = (const float*)d_in[7];
    const float* g_w2  = (const float*)d_in[8];
    const float* g_b2  = (const float*)d_in[9];
    const float* g_w3  = (const float*)d_in[10];
    const float* g_b3  = (const float*)d_in[11];
    const float* g_w4  = (const float*)d_in[12];
    const float* g_b4  = (const float*)d_in[13];
    const float* f_w1  = (const float*)d_in[14];
    const float* f_b1  = (const float*)d_in[15];
    const float* f_w2  = (const float*)d_in[16];
    const float* f_b2  = (const float*)d_in[17];
    const float* f_w3  = (const float*)d_in[18];
    const float* f_b3  = (const float*)d_in[19];
    const int* q_feats = (const int*)d_in[20];
    const int* q_lens  = (const int*)d_in[21];
    float* out = (float*)d_out;

    char* ws = (char*)d_ws;
    float*  P    = (float*) (ws + 0);          //  96*512*4      = 196608
    float*  Wq   = (float*) (ws + 196608);     // 128*256*4      = 131072
    ushort* A1   = (ushort*)(ws + 327680);     // 8192*256*2     = 4194304
    ushort* A2   = (ushort*)(ws + 4521984);    // 8192*256*2     = 4194304
    ushort* Wst  = (ushort*)(ws + 8716288);    // 3*65536*2      = 393216
    float*  part = (float*) (ws + 9109504);    // 8192*256*4     = 8388608
    float*  gout = (float*) (ws + 17498112);   // 128*256*4      = 131072

    hipLaunchKernelGGL(kP,    dim3(96),   dim3(512), 0, stream, emb, w_ih, b_ih, P);
    hipLaunchKernelGGL(kW,    dim3(24),   dim3(256), 0, stream, g_w2, g_w3, g_w4, Wst);
    hipLaunchKernelGGL(kLSTM, dim3(128),  dim3(256), 0, stream, P, w_hh, b_hh, g_w1, g_b1, q_feats, q_lens, Wq);
    hipLaunchKernelGGL(kA,    dim3(8192), dim3(256), 0, stream, box_feats, g_w1, Wq, A1, A2);
    hipLaunchKernelGGL(kD,    dim3(8192), dim3(256), 0, stream, A1, A2, Wst, g_b2, g_b3, g_b4, part);
    hipLaunchKernelGGL(kR,    dim3(128),  dim3(256), 0, stream, part, gout);
    hipLaunchKernelGGL(kF,    dim3(128),  dim3(256), 0, stream, gout, f_w1, f_b1, f_w2, f_b2, f_w3, f_b3, out);
}